// Round 6
// baseline (86311.145 us; speedup 1.0000x reference)
//
#include <hip/hip_runtime.h>
#include <stdint.h>

// Transducer greedy decode, persistent 3-stage pipeline (R10).
// R9 never ran (container failed twice; infra push times degraded 5x the
// same rounds -> infra-flake hypothesis; deadlock re-audit found no cycle).
// R10 = R9 self-timed design, improved: the epoch-scan is FUSED into the
// gather. Each poll round loads the 80 (value,epoch) words once, checks
// epochs AND accumulates (FMA / LDS-stash) in the same pass; on any stale
// epoch the accumulator is reset and the round retried (idempotent).
// Halves R9's poll traffic and removes one serial RT -> exchange =
// store-travel + ONE payload RT (the floor for this pattern).
// Lineage recap: R4/R5/R6 all ~9us/exchange across 3 flag topologies ->
// cost is ~4 serial fabric RTs (drain ack, fanout, discovery, gather).
// Self-timed words remove drain/fanout/discovery. R7/R8: sub-8B
// multi-writer words corrupt; ALL shared words here are 8B single-writer
// (R5-LKEY-validated pattern). No fences: agent-scope relaxed bypasses
// L1/L2 (consumer acquire would evict L2-resident weight slices).
// LKEY carries a 10-bit epoch in low bits (ordering (m,1023-v) preserved);
// LSE=(se,epoch); XZ/XH parity double-buffered; epochs re-stamped by
// k_init each launch (replay-safe, R4/R5-validated flush pattern).
// Stages (224 blk x 256 thr, 1 blk/CU): A(80): z=tanh(Wtn.x+Wpn.h+bj)
// L(64): logits -> per-block argmax/sumexp slots; C(80): Whh.h +
// slot-reduce + decode + LSTM elementwise.
// Chain: C(t-1) h -> A(t) z -> L(t) logits -> C-tail(t).

typedef unsigned long long u64;
typedef uint32_t u32;

#define TT 1000
#define DD 640
#define GG 2560
#define VV 1024

#define NA 80
#define NL 64
#define NC 80
#define NBLK (NA + NL + NC) // 224

// ws layout (float offsets)
static constexpr size_t OFF_WTN  = 0;                      // 640x640  WT4
static constexpr size_t OFF_WPN  = OFF_WTN  + 409600;
static constexpr size_t OFF_WHH  = OFF_WPN  + 409600;      // 2560x640
static constexpr size_t OFF_WOUT = OFF_WHH  + 1638400;     // 1024x640
static constexpr size_t OFF_P    = OFF_WOUT + 655360;      // 1024x2560
// self-timed (value,epoch) u64 arrays:
static constexpr size_t OFF_XH   = OFF_P    + 2621440;     // u64[2][32][640]
static constexpr size_t OFF_XZ   = OFF_XH   + 81920;       // u64[2][32][640]
static constexpr size_t OFF_SC   = OFF_XZ   + 81920;       // f32 score[32]
static constexpr size_t OFF_LKEY = OFF_SC   + 32;          // u64[32][64]
static constexpr size_t OFF_LSE  = OFF_LKEY + 4096;        // u64[32][64]
static constexpr size_t OFF_END  = OFF_LSE  + 4096;        // ~23.6 MB

__device__ __forceinline__ float sigf(float x) { return 1.0f / (1.0f + expf(-x)); }

__device__ __forceinline__ u32 ordf(float f) {
  u32 u = __float_as_uint(f);
  return (u & 0x80000000u) ? ~u : (u | 0x80000000u);
}

// ---- coherent (MALL) accesses: bypass L1/L2, no fences ----
__device__ __forceinline__ u64 cloadu64(const u64* p) {
  return __hip_atomic_load(p, __ATOMIC_RELAXED, __HIP_MEMORY_SCOPE_AGENT);
}
__device__ __forceinline__ void cstoreu64(u64* p, u64 v) {
  __hip_atomic_store(p, v, __ATOMIC_RELAXED, __HIP_MEMORY_SCOPE_AGENT);
}
// (value, epoch) packing: low 32 = float bits, high 32 = epoch
__device__ __forceinline__ u64 packfe(float f, int e) {
  return ((u64)(u32)e << 32) | (u64)__float_as_uint(f);
}
__device__ __forceinline__ float valof(u64 w) { return __uint_as_float((u32)w); }
__device__ __forceinline__ int epof(u64 w) { return (int)(u32)(w >> 32); }

__device__ __forceinline__ void fma4(float& a, const float4 w, const float4 x) {
  a = fmaf(w.x, x.x, fmaf(w.y, x.y, fmaf(w.z, x.z, fmaf(w.w, x.w, a))));
}
__device__ __forceinline__ void fma22(float& a, const float4 w, const float2 xa,
                                      const float2 xb) {
  a = fmaf(w.x, xa.x, fmaf(w.y, xa.y, fmaf(w.z, xb.x, fmaf(w.w, xb.y, a))));
}

// ---- setup kernels ----

// W[j][d] (row-major, K=640) -> WT4: float4 at (d/4)*J + j holds W[j][4q..4q+3]
__global__ __launch_bounds__(256) void k_wt4(const float* __restrict__ W,
                                             float* __restrict__ WT4, int J) {
  __shared__ float tile[64][65];
  int nj = J >> 6;
  int tj = blockIdx.x % nj, tk = blockIdx.x / nj;
  int jb = tj << 6, kb = tk << 6;
  for (int i = threadIdx.x; i < 4096; i += 256) {
    int d = i & 63, j = i >> 6;
    tile[j][d] = W[(size_t)(jb + j) * DD + (kb + d)];
  }
  __syncthreads();
  for (int i = threadIdx.x; i < 1024; i += 256) {
    int j = i & 63, q = i >> 6;
    float4 v = make_float4(tile[j][q * 4], tile[j][q * 4 + 1], tile[j][q * 4 + 2],
                           tile[j][q * 4 + 3]);
    ((float4*)WT4)[(size_t)((kb >> 2) + q) * J + (jb + j)] = v;
  }
}

// P[v][g] = sum_d E[v][d] * Wih[g][d]
__global__ __launch_bounds__(256) void k_pgemm(const float* __restrict__ E,
                                               const float* __restrict__ Wih,
                                               float* __restrict__ P) {
  __shared__ float As[16][65], Bs[16][65];
  int vt = blockIdx.x & 15, gt = blockIdx.x >> 4;
  int vb = vt << 6, gb = gt << 6;
  int tv = threadIdx.x & 15, tg = threadIdx.x >> 4;
  float acc[4][4] = {};
  for (int kb = 0; kb < DD; kb += 16) {
    for (int i = threadIdx.x; i < 1024; i += 256) {
      int k = i & 15, x = i >> 4;
      As[k][x] = E[(size_t)(vb + x) * DD + kb + k];
      Bs[k][x] = Wih[(size_t)(gb + x) * DD + kb + k];
    }
    __syncthreads();
#pragma unroll
    for (int k = 0; k < 16; ++k) {
      float av[4], bv[4];
#pragma unroll
      for (int i = 0; i < 4; ++i) av[i] = As[k][tv * 4 + i];
#pragma unroll
      for (int j = 0; j < 4; ++j) bv[j] = Bs[k][tg * 4 + j];
#pragma unroll
      for (int i = 0; i < 4; ++i)
#pragma unroll
        for (int j = 0; j < 4; ++j) acc[i][j] = fmaf(av[i], bv[j], acc[i][j]);
    }
    __syncthreads();
  }
#pragma unroll
  for (int i = 0; i < 4; ++i)
#pragma unroll
    for (int j = 0; j < 4; ++j)
      P[(size_t)(vb + tv * 4 + i) * GG + gb + tg * 4 + j] = acc[i][j];
}

// initial LSTM step -> XH parity 0 stamped epoch 0; invalidate all other
// epochs (plain stores; kernel-boundary flush -- validated pattern).
__global__ __launch_bounds__(256) void k_init(float* __restrict__ ws,
                                              const float* __restrict__ bl) {
  const float* P = ws + OFF_P;
  u64* XHu = (u64*)(ws + OFF_XH);
  u64* XZu = (u64*)(ws + OFF_XZ);
  u64* LKu = (u64*)(ws + OFF_LKEY);
  u64* LSu = (u64*)(ws + OFF_LSE);
  int tid = blockIdx.x * 256 + threadIdx.x;
  if (tid < DD) {
    int j = tid;
    float gi = P[j] + bl[j];
    float gg = P[1280 + j] + bl[1280 + j];
    float go = P[1920 + j] + bl[1920 + j];
    float c1 = sigf(gi) * tanhf(gg);
    float h1 = sigf(go) * tanhf(c1);
    for (int b = 0; b < 32; ++b) XHu[(size_t)b * 640 + j] = packfe(h1, 0);
  }
  const u64 inval = packfe(0.f, -1);
  for (int i = tid; i < 20480; i += 1024) XHu[20480 + i] = inval; // parity 1
  for (int i = tid; i < 40960; i += 1024) XZu[i] = inval;
  for (int i = tid; i < 2048; i += 1024) LKu[i] = 0x3FFull; // epoch 1023
  for (int i = tid; i < 2048; i += 1024) LSu[i] = inval;
}

// ---- persistent decode ----
__global__ __launch_bounds__(256, 1) void k_decode(float* __restrict__ ws,
                                                   const float* __restrict__ tn,
                                                   const float* __restrict__ bl,
                                                   const float* __restrict__ bj,
                                                   const float* __restrict__ bo,
                                                   float* __restrict__ out) {
  const float* WTN = ws + OFF_WTN;
  const float* WPN = ws + OFF_WPN;
  const float* WHH = ws + OFF_WHH;
  const float* WOUT = ws + OFF_WOUT;
  const float* P = ws + OFF_P;
  u64* XHu = (u64*)(ws + OFF_XH);
  u64* XZu = (u64*)(ws + OFF_XZ);
  float* SCg = ws + OFF_SC;
  u64* LKu = (u64*)(ws + OFF_LKEY);
  u64* LSu = (u64*)(ws + OFF_LSE);

  // ~124 KB static LDS: functional + forces 1 block/CU (exclusive residency).
  __shared__ float xbuf[32 * 648];     // C: h stash (16B-aligned rows)
  __shared__ float red[16 * 16 * 33];  // partial sums
  __shared__ float aux[32 * 33];       // A: z rows; L: logit tile; C: gates
  __shared__ u64 kred[32 * 9];
  __shared__ float sered[32 * 9];
  __shared__ float c_lds[8 * 33], h_lds[8 * 33];
  __shared__ float sc_lds[32];
  __shared__ int tok_lds[32], nb_lds[32], lt_lds[32];

  const int bid = blockIdx.x, tid = threadIdx.x;
  const int dq = tid >> 4, bp = tid & 15; // 16 d-groups x 16 b-pairs
  const int d0 = dq * 40, b0 = bp * 2;

  if (bid < NA) {
    // ---- stage A: XZ = tanh(W_tn.tn_t + W_pn.h + b_joint), 8 j rows ----
    const int j0 = bid * 8;
    for (int t = 0; t < TT; ++t) {
      const int par = t & 1;
      // (1) Wtn partials first: immutable input, off the critical path.
      float acc_tn[8][2] = {};
      const float* t0p = tn + ((size_t)b0 * TT + t) * DD + d0;
      const float* t1p = t0p + (size_t)TT * DD;
#pragma unroll 5
      for (int q = 0; q < 10; ++q) {
        float4 x0 = *(const float4*)(t0p + q * 4);
        float4 x1 = *(const float4*)(t1p + q * 4);
        const float4* wt = (const float4*)WTN + (size_t)((d0 + q * 4) >> 2) * DD + j0;
#pragma unroll
        for (int r = 0; r < 8; ++r) {
          fma4(acc_tn[r][0], wt[r], x0);
          fma4(acc_tn[r][1], wt[r], x1);
        }
      }
      // (2) FUSED self-timed wait+gather+FMA of h(t): one payload RT/round.
      const u64* h0p = XHu + (size_t)par * 20480 + (size_t)b0 * 640 + d0;
      const u64* h1p = h0p + 640;
      float acc[8][2];
      for (;;) {
        u32 bad = 0;
#pragma unroll
        for (int r = 0; r < 8; ++r) {
          acc[r][0] = acc_tn[r][0];
          acc[r][1] = acc_tn[r][1];
        }
#pragma unroll 5
        for (int q = 0; q < 10; ++q) {
          u64 w0 = cloadu64(h0p + q * 4), w1 = cloadu64(h0p + q * 4 + 1);
          u64 w2 = cloadu64(h0p + q * 4 + 2), w3 = cloadu64(h0p + q * 4 + 3);
          u64 y0 = cloadu64(h1p + q * 4), y1 = cloadu64(h1p + q * 4 + 1);
          u64 y2 = cloadu64(h1p + q * 4 + 2), y3 = cloadu64(h1p + q * 4 + 3);
          bad |= (u32)(epof(w0) != t) | (u32)(epof(w1) != t) |
                 (u32)(epof(w2) != t) | (u32)(epof(w3) != t) |
                 (u32)(epof(y0) != t) | (u32)(epof(y1) != t) |
                 (u32)(epof(y2) != t) | (u32)(epof(y3) != t);
          float2 a0 = make_float2(valof(w0), valof(w1));
          float2 a1 = make_float2(valof(w2), valof(w3));
          float2 b1 = make_float2(valof(y0), valof(y1));
          float2 b2 = make_float2(valof(y2), valof(y3));
          const float4* wp =
              (const float4*)WPN + (size_t)((d0 + q * 4) >> 2) * DD + j0;
#pragma unroll
          for (int r = 0; r < 8; ++r) {
            fma22(acc[r][0], wp[r], a0, a1);
            fma22(acc[r][1], wp[r], b1, b2);
          }
        }
        if (!bad) break;
        __builtin_amdgcn_s_sleep(2);
      }
#pragma unroll
      for (int r = 0; r < 8; ++r) {
        red[(dq * 8 + r) * 33 + b0] = acc[r][0];
        red[(dq * 8 + r) * 33 + b0 + 1] = acc[r][1];
      }
      __syncthreads();
      {
        int r = tid >> 5, b = tid & 31;
        float s = 0.f;
#pragma unroll
        for (int k = 0; k < 16; ++k) s += red[(k * 8 + r) * 33 + b];
        aux[r * 33 + b] = tanhf(s + bj[j0 + r]);
      }
      __syncthreads();
      if (tid < 128) {
        int jp = tid >> 5, b = tid & 31;
        u64* zp = XZu + (size_t)par * 20480 + (size_t)b * 640 + j0 + jp * 2;
        cstoreu64(zp, packfe(aux[(jp * 2) * 33 + b], t));
        cstoreu64(zp + 1, packfe(aux[(jp * 2 + 1) * 33 + b], t));
      }
      // no publish, no drain: stores are self-timed.
    }
  } else if (bid < NA + NL) {
    // ---- stage L: 16-v logit tile -> per-block slots (zero-RMW) ----
    const int lb = bid - NA, v0 = lb * 16;
    for (int t = 0; t < TT; ++t) {
      const int par = t & 1;
      const u64* z0p = XZu + (size_t)par * 20480 + (size_t)b0 * 640 + d0;
      const u64* z1p = z0p + 640;
      // FUSED self-timed wait+gather+FMA of z(t).
      float acc[16][2];
      for (;;) {
        u32 bad = 0;
#pragma unroll
        for (int r = 0; r < 16; ++r) acc[r][0] = acc[r][1] = 0.f;
#pragma unroll 5
        for (int q = 0; q < 10; ++q) {
          u64 w0 = cloadu64(z0p + q * 4), w1 = cloadu64(z0p + q * 4 + 1);
          u64 w2 = cloadu64(z0p + q * 4 + 2), w3 = cloadu64(z0p + q * 4 + 3);
          u64 y0 = cloadu64(z1p + q * 4), y1 = cloadu64(z1p + q * 4 + 1);
          u64 y2 = cloadu64(z1p + q * 4 + 2), y3 = cloadu64(z1p + q * 4 + 3);
          bad |= (u32)(epof(w0) != t) | (u32)(epof(w1) != t) |
                 (u32)(epof(w2) != t) | (u32)(epof(w3) != t) |
                 (u32)(epof(y0) != t) | (u32)(epof(y1) != t) |
                 (u32)(epof(y2) != t) | (u32)(epof(y3) != t);
          float2 z0a = make_float2(valof(w0), valof(w1));
          float2 z0b = make_float2(valof(w2), valof(w3));
          float2 z1a = make_float2(valof(y0), valof(y1));
          float2 z1b = make_float2(valof(y2), valof(y3));
          const float4* wo =
              (const float4*)WOUT + (size_t)((d0 + q * 4) >> 2) * VV + v0;
#pragma unroll
          for (int r = 0; r < 16; ++r) {
            float4 w = wo[r];
            fma22(acc[r][0], w, z0a, z0b);
            fma22(acc[r][1], w, z1a, z1b);
          }
        }
        if (!bad) break;
        __builtin_amdgcn_s_sleep(2);
      }
#pragma unroll
      for (int r = 0; r < 16; ++r) {
        red[(dq * 16 + r) * 33 + b0] = acc[r][0];
        red[(dq * 16 + r) * 33 + b0 + 1] = acc[r][1];
      }
      __syncthreads();
#pragma unroll
      for (int o = tid; o < 512; o += 256) {
        int r = o >> 5, b = o & 31;
        float s = bo[v0 + r];
#pragma unroll
        for (int k = 0; k < 16; ++k) s += red[(k * 16 + r) * 33 + b];
        aux[r * 33 + b] = s;
      }
      __syncthreads();
      if (tid < 32) {
        int b = tid;
        float m = -1e30f, se = 0.f;
        int vbest = 0;
#pragma unroll
        for (int r = 0; r < 16; ++r) {
          float x = aux[r * 33 + b];
          se += expf(x);
          if (x > m) { m = x; vbest = r; } // strict > => first occurrence
        }
        // key: [63:32]=ordf(m), [29:20]=1023-v (smaller v wins ties),
        // [9:0]=epoch t. Epoch bits below v bits -> ordering preserved.
        u64 key = ((u64)ordf(m) << 32) | ((u64)(1023 - (v0 + vbest)) << 20) |
                  (u64)t;
        cstoreu64(&LKu[(size_t)b * 64 + lb], key);
        cstoreu64(&LSu[(size_t)b * 64 + lb], packfe(se, t));
      }
    }
  } else {
    // ---- stage C: gates = W_hh.h (LDS-stashed h, 2 passes of 16 rows),
    //      slot-reduce argmax, decode, LSTM elementwise ----
    const int cb = bid - (NA + NL), j0 = cb * 8;
    {
      int jj = tid >> 5, b = tid & 31, j = j0 + jj;
      float gi = P[j] + bl[j];
      float gg = P[1280 + j] + bl[1280 + j];
      float go = P[1920 + j] + bl[1920 + j];
      float c1 = sigf(gi) * tanhf(gg);
      c_lds[jj * 33 + b] = c1;
      h_lds[jj * 33 + b] = sigf(go) * tanhf(c1);
    }
    if (tid < 32) { lt_lds[tid] = 0; sc_lds[tid] = 0.f; }
    __syncthreads();
    for (int t = 0; t < TT; ++t) {
      const int par = t & 1;
      // FUSED self-timed wait+gather of h(t) into the LDS stash.
      const u64* h0p = XHu + (size_t)par * 20480 + (size_t)b0 * 640 + d0;
      const u64* h1p = h0p + 640;
      for (;;) {
        u32 bad = 0;
#pragma unroll 5
        for (int q = 0; q < 10; ++q) {
          u64 w0 = cloadu64(h0p + q * 4), w1 = cloadu64(h0p + q * 4 + 1);
          u64 w2 = cloadu64(h0p + q * 4 + 2), w3 = cloadu64(h0p + q * 4 + 3);
          u64 y0 = cloadu64(h1p + q * 4), y1 = cloadu64(h1p + q * 4 + 1);
          u64 y2 = cloadu64(h1p + q * 4 + 2), y3 = cloadu64(h1p + q * 4 + 3);
          bad |= (u32)(epof(w0) != t) | (u32)(epof(w1) != t) |
                 (u32)(epof(w2) != t) | (u32)(epof(w3) != t) |
                 (u32)(epof(y0) != t) | (u32)(epof(y1) != t) |
                 (u32)(epof(y2) != t) | (u32)(epof(y3) != t);
          *(float4*)&xbuf[b0 * 648 + d0 + q * 4] =
              make_float4(valof(w0), valof(w1), valof(w2), valof(w3));
          *(float4*)&xbuf[(b0 + 1) * 648 + d0 + q * 4] =
              make_float4(valof(y0), valof(y1), valof(y2), valof(y3));
        }
        if (!bad) break;
        __builtin_amdgcn_s_sleep(2);
      }
      __syncthreads();
#pragma unroll
      for (int p = 0; p < 2; ++p) {
        float acc[16][2] = {};
#pragma unroll 5
        for (int q = 0; q < 10; ++q) {
          const int d = d0 + q * 4;
          float4 h0 = *(const float4*)&xbuf[b0 * 648 + d];
          float4 h1 = *(const float4*)&xbuf[(b0 + 1) * 648 + d];
          const float4* wa =
              (const float4*)WHH + (size_t)(d >> 2) * GG + (2 * p) * DD + j0;
          const float4* wb = wa + DD;
#pragma unroll
          for (int jj = 0; jj < 8; ++jj) {
            fma4(acc[jj][0], wa[jj], h0);
            fma4(acc[jj][1], wa[jj], h1);
            fma4(acc[8 + jj][0], wb[jj], h0);
            fma4(acc[8 + jj][1], wb[jj], h1);
          }
        }
#pragma unroll
        for (int r = 0; r < 16; ++r) {
          red[(dq * 16 + r) * 33 + b0] = acc[r][0];
          red[(dq * 16 + r) * 33 + b0 + 1] = acc[r][1];
        }
        __syncthreads();
#pragma unroll
        for (int o = tid; o < 512; o += 256) {
          int r16 = o >> 5, b = o & 31;
          float s = 0.f;
#pragma unroll
          for (int k = 0; k < 16; ++k) s += red[(k * 16 + r16) * 33 + b];
          int g = 2 * p + (r16 >> 3), jj = r16 & 7;
          aux[(g * 8 + jj) * 33 + b] = s; // gates
        }
        __syncthreads();
      }
      // FUSED self-timed wait+reduce of logits(t) slots.
      {
        int b = tid >> 3, ch = tid & 7;
        const u64* kp = LKu + (size_t)b * 64 + ch * 8;
        const u64* sp = LSu + (size_t)b * 64 + ch * 8;
        u64 km;
        float ss;
        for (;;) {
          u32 bad = 0;
          km = 0;
          ss = 0.f;
#pragma unroll
          for (int i = 0; i < 8; ++i) {
            u64 x = cloadu64(kp + i);
            bad |= (u32)((x & 0x3FFull) != (u64)t);
            km = x > km ? x : km;
          }
          if (cb == 0) {
#pragma unroll
            for (int i = 0; i < 8; ++i) {
              u64 w = cloadu64(sp + i);
              bad |= (u32)(epof(w) != t);
              ss += valof(w);
            }
          }
          if (!bad) break;
          __builtin_amdgcn_s_sleep(2);
        }
        kred[b * 9 + ch] = km;
        if (cb == 0) sered[b * 9 + ch] = ss;
      }
      __syncthreads();
      if (tid < 32) {
        int b = tid;
        u64 km = 0;
#pragma unroll
        for (int ch = 0; ch < 8; ++ch) {
          u64 x = kred[b * 9 + ch];
          km = x > km ? x : km;
        }
        u32 ou = (u32)(km >> 32);
        u32 fb = (ou & 0x80000000u) ? (ou & 0x7FFFFFFFu) : ~ou;
        float m = __uint_as_float(fb);
        int v = 1023 - (int)((km >> 20) & 0x3FF);
        int nb = (v != 0) ? 1 : 0;
        int tok = nb ? v : lt_lds[b];
        lt_lds[b] = tok;
        tok_lds[b] = tok;
        nb_lds[b] = nb;
        if (cb == 0) {
          float S = 0.f;
#pragma unroll
          for (int ch = 0; ch < 8; ++ch) S += sered[b * 9 + ch];
          float lp = m - logf(S); // logits bounded: no max-shift needed
          if (nb) sc_lds[b] += lp;
          out[(size_t)b * TT + t] = nb ? (float)v : 0.0f;
          if (t == TT - 1) SCg[b] = sc_lds[b];
        }
      }
      __syncthreads();
      {
        int jj = tid >> 5, b = tid & 31, j = j0 + jj;
        if (nb_lds[b]) {
          const float* Pr = P + (size_t)tok_lds[b] * GG;
          float gi = aux[(0 + jj) * 33 + b] + Pr[j] + bl[j];
          float gf = aux[(8 + jj) * 33 + b] + Pr[640 + j] + bl[640 + j];
          float gg = aux[(16 + jj) * 33 + b] + Pr[1280 + j] + bl[1280 + j];
          float go = aux[(24 + jj) * 33 + b] + Pr[1920 + j] + bl[1920 + j];
          float c = c_lds[jj * 33 + b];
          float cn = sigf(gf) * c + sigf(gi) * tanhf(gg);
          float hn = sigf(go) * tanhf(cn);
          c_lds[jj * 33 + b] = cn;
          h_lds[jj * 33 + b] = hn;
        }
      }
      __syncthreads();
      if (tid < 128) {
        int jp = tid >> 5, b = tid & 31;
        u64* hp = XHu + (size_t)(1 - par) * 20480 + (size_t)b * 640 + j0 + jp * 2;
        cstoreu64(hp, packfe(h_lds[(jp * 2) * 33 + b], t + 1));
        cstoreu64(hp + 1, packfe(h_lds[(jp * 2 + 1) * 33 + b], t + 1));
      }
      // no publish, no drain: stores are self-timed.
    }
  }
}

__global__ __launch_bounds__(64) void k_final(const float* __restrict__ ws,
                                              float* __restrict__ out) {
  __shared__ float sh[32];
  int t = threadIdx.x;
  if (t < 32) {
    float s = ws[OFF_SC + t];
    out[32000 + t] = s;
    sh[t] = expf(s);
  }
  __syncthreads();
  if (t == 0) {
    float a = 0.f;
    for (int i = 0; i < 32; ++i) a += sh[i];
    out[32032] = a / 32.0f;
  }
}

extern "C" void kernel_launch(void* const* d_in, const int* in_sizes, int n_in,
                              void* d_out, int out_size, void* d_ws, size_t ws_size,
                              hipStream_t stream) {
  const float* tn = (const float*)d_in[0];
  const float* E = (const float*)d_in[1];
  const float* Wih = (const float*)d_in[2];
  const float* Whh = (const float*)d_in[3];
  const float* bl = (const float*)d_in[4];
  const float* Wtn = (const float*)d_in[5];
  const float* Wpn = (const float*)d_in[6];
  const float* bj = (const float*)d_in[7];
  const float* Wout = (const float*)d_in[8];
  const float* bo = (const float*)d_in[9];
  float* ws = (float*)d_ws;
  float* out = (float*)d_out;

  k_wt4<<<100, 256, 0, stream>>>(Wtn, ws + OFF_WTN, DD);
  k_wt4<<<100, 256, 0, stream>>>(Wpn, ws + OFF_WPN, DD);
  k_wt4<<<400, 256, 0, stream>>>(Whh, ws + OFF_WHH, GG);
  k_wt4<<<160, 256, 0, stream>>>(Wout, ws + OFF_WOUT, VV);
  k_pgemm<<<640, 256, 0, stream>>>(E, Wih, ws + OFF_P);
  k_init<<<4, 256, 0, stream>>>(ws, bl);
  k_decode<<<NBLK, 256, 0, stream>>>(ws, tn, bl, bj, bo, out);
  k_final<<<1, 64, 0, stream>>>(ws, out);
}